// Round 2
// baseline (140.431 us; speedup 1.0000x reference)
//
#include <hip/hip_runtime.h>
#include <hip/hip_bf16.h>

// Problem constants (fixed by setup_inputs)
constexpr int B  = 32;
constexpr int H  = 640;
constexpr int Wd = 640;
constexpr int M  = 256;

constexpr int CHUNKS       = 100;                 // blocks per image
constexpr int F4_PER_IMG   = H * Wd / 4;          // 102400
constexpr int F4_PER_BLOCK = F4_PER_IMG / CHUNKS; // 1024 float4 per block
constexpr int NBLK         = B * CHUNKS;          // 3200 blocks

// Workspace layout (bytes):
//   [0,4)    : unsigned counter (memset to 0 each call via hipMemsetAsync)
//   [64, 64+NBLK*4) : float partials[NBLK]
constexpr size_t WS_PARTIALS_OFF = 64;

// ---------------------------------------------------------------------------
// Single fused kernel.
//  - Each block derives the box list for its image from bboxes (4 KB,
//    L2-resident) — no producer kernel needed.
//  - Streams 4096 pixels (1024 float4), computes BCE terms, block-reduces.
//  - Last arriving block (device atomic counter) does the deterministic
//    fixed-order f64 reduction of all partials and writes the scalar.
// ---------------------------------------------------------------------------
__global__ __launch_bounds__(256) void fused_bce(
    const float* __restrict__ seg_preds,
    const float* __restrict__ bboxes,
    const int* __restrict__ batch_idx,
    const unsigned char* __restrict__ is_seg,
    unsigned int* __restrict__ counter,
    float* __restrict__ partials,
    float* __restrict__ out)
{
    const int img   = blockIdx.x / CHUNKS;
    const int chunk = blockIdx.x % CHUNKS;

    __shared__ ushort4 sbox[M];
    __shared__ int scount;
    __shared__ float wsum[4];
    __shared__ int islast;
    __shared__ double sd[256];

    // pixel range of this block -> row range
    const int p_start = chunk * F4_PER_BLOCK * 4;
    const int row_lo  = p_start / Wd;
    const int row_hi  = (p_start + F4_PER_BLOCK * 4 - 1) / Wd;

    if (threadIdx.x == 0) scount = 0;
    __syncthreads();

    // ---- derive this image's row-overlapping boxes (bit-identical f32 math)
    if (threadIdx.x < M) {
        const float4 bb = ((const float4*)bboxes)[threadIdx.x];
        if (batch_idx[threadIdx.x] == img) {
            float cx = bb.x * 640.0f, cy = bb.y * 640.0f;
            float bw = bb.z * 640.0f, bh = bb.w * 640.0f;
            float x1f = fminf(fmaxf(cx - bw * 0.5f, 0.0f), 639.0f);
            float y1f = fminf(fmaxf(cy - bh * 0.5f, 0.0f), 639.0f);
            float x2f = fminf(fmaxf(cx + bw * 0.5f, 0.0f), 639.0f);
            float y2f = fminf(fmaxf(cy + bh * 0.5f, 0.0f), 639.0f);
            int y1 = (int)y1f, y2 = (int)y2f;
            if (y1 <= row_hi && y2 >= row_lo) {
                ushort4 bx;
                bx.x = (unsigned short)(int)x1f;
                bx.y = (unsigned short)y1;
                bx.z = (unsigned short)(int)x2f;
                bx.w = (unsigned short)y2;
                int slot = atomicAdd(&scount, 1);  // order-independent union
                sbox[slot] = bx;
            }
        }
    }
    __syncthreads();
    const int  ncnt = scount;
    const bool det  = (is_seg[img] == 0);

    const float4* __restrict__ xin =
        (const float4*)(seg_preds + (size_t)img * H * Wd);

    // ---- streaming BCE partial (same per-pixel math as R1: absmax was 0.0)
    float acc = 0.0f;
    #pragma unroll
    for (int k = 0; k < 4; ++k) {
        const int    f4 = chunk * F4_PER_BLOCK + k * 256 + threadIdx.x;
        const float4 v  = xin[f4];
        const int p   = f4 * 4;
        const int row = p / Wd;
        const int col = p - row * Wd;

        unsigned covm = 0u;
        if (det) {
            for (int i = 0; i < ncnt; ++i) {
                ushort4 bx = sbox[i];
                if (row >= (int)bx.y && row <= (int)bx.w) {
                    int lo = max((int)bx.x - col, 0);
                    int hi = min((int)bx.z - col, 3);
                    if (lo <= hi) covm |= ((1u << (hi - lo + 1)) - 1u) << lo;
                    if (covm == 0xFu) break;
                }
            }
        }
        const float vals[4] = {v.x, v.y, v.z, v.w};
        #pragma unroll
        for (int j = 0; j < 4; ++j) {
            float xv = vals[j];
            float a  = fabsf(xv);
            float sp = __logf(1.0f + __expf(-a));
            float term = fmaxf(xv, 0.0f) + sp;
            if (covm & (1u << j)) term -= xv;
            acc += term;
        }
    }

    // ---- block reduce (wave64 shuffle, then 4 waves)
    for (int off = 32; off > 0; off >>= 1)
        acc += __shfl_down(acc, off, 64);
    const int lane = threadIdx.x & 63;
    const int wid  = threadIdx.x >> 6;
    if (lane == 0) wsum[wid] = acc;
    __syncthreads();

    if (threadIdx.x == 0) {
        float p = wsum[0] + wsum[1] + wsum[2] + wsum[3];
        // system-scope store: visible across XCDs before the counter bump
        __hip_atomic_store(&partials[blockIdx.x], p,
                           __ATOMIC_RELEASE, __HIP_MEMORY_SCOPE_SYSTEM);
        unsigned old = __hip_atomic_fetch_add(counter, 1u,
                           __ATOMIC_ACQ_REL, __HIP_MEMORY_SCOPE_SYSTEM);
        islast = (old == (unsigned)(NBLK - 1)) ? 1 : 0;
    }
    __syncthreads();
    if (!islast) return;

    // ---- last block: deterministic fixed-order f64 reduction
    double s = 0.0;
    for (int i = threadIdx.x; i < NBLK; i += 256)
        s += (double)__hip_atomic_load(&partials[i],
                         __ATOMIC_RELAXED, __HIP_MEMORY_SCOPE_SYSTEM);
    sd[threadIdx.x] = s;
    __syncthreads();
    for (int off = 128; off > 0; off >>= 1) {
        if (threadIdx.x < off) sd[threadIdx.x] += sd[threadIdx.x + off];
        __syncthreads();
    }
    if (threadIdx.x == 0) {
        int nd = 0;
        for (int b = 0; b < B; ++b) nd += (is_seg[b] == 0) ? 1 : 0;
        double hd   = (nd > 0) ? 1.0 : 0.0;
        double mean = sd[0] / (double)((size_t)B * H * Wd);
        out[0] = (float)(0.1 * mean * hd);
    }
}

extern "C" void kernel_launch(void* const* d_in, const int* in_sizes, int n_in,
                              void* d_out, int out_size, void* d_ws, size_t ws_size,
                              hipStream_t stream)
{
    const float*         seg_preds = (const float*)d_in[0];
    const float*         bboxes    = (const float*)d_in[1];
    const int*           batch_idx = (const int*)d_in[2];
    const unsigned char* is_seg    = (const unsigned char*)d_in[3];

    unsigned int* counter  = (unsigned int*)d_ws;
    float*        partials = (float*)((char*)d_ws + WS_PARTIALS_OFF);
    float*        out      = (float*)d_out;

    hipMemsetAsync(counter, 0, sizeof(unsigned int), stream);
    fused_bce<<<NBLK, 256, 0, stream>>>(seg_preds, bboxes, batch_idx, is_seg,
                                        counter, partials, out);
}

// Round 3
// 26.731 us; speedup vs baseline: 5.2534x; 5.2534x over previous
//
#include <hip/hip_runtime.h>
#include <hip/hip_bf16.h>

// Problem constants (fixed by setup_inputs)
constexpr int B  = 32;
constexpr int H  = 640;
constexpr int Wd = 640;
constexpr int M  = 256;

constexpr int CHUNKS       = 100;                 // blocks per image
constexpr int F4_PER_IMG   = H * Wd / 4;          // 102400
constexpr int F4_PER_BLOCK = F4_PER_IMG / CHUNKS; // 1024 float4 per block
constexpr int NBLK         = B * CHUNKS;          // 3200 blocks

// Workspace layout (bytes): [64, 64+NBLK*4) : float partials[NBLK]
constexpr size_t WS_PARTIALS_OFF = 64;

// ---------------------------------------------------------------------------
// Kernel 1: streaming BCE partials. Each block derives its image's
// row-overlapping boxes from bboxes (4 KB, L2-resident), streams 4096
// pixels (1024 float4), block-reduces, plain-stores one float partial.
// No global atomics, no fences — cross-kernel visibility comes from the
// graph edge (R2 lesson: per-block system-scope fences cost ~120 us).
// ---------------------------------------------------------------------------
__global__ __launch_bounds__(256) void bce_partial(
    const float* __restrict__ seg_preds,
    const float* __restrict__ bboxes,
    const int* __restrict__ batch_idx,
    const unsigned char* __restrict__ is_seg,
    float* __restrict__ partials)
{
    const int img   = blockIdx.x / CHUNKS;
    const int chunk = blockIdx.x % CHUNKS;

    __shared__ ushort4 sbox[M];
    __shared__ int scount;
    __shared__ float wsum[4];

    // pixel range of this block -> row range
    const int p_start = chunk * F4_PER_BLOCK * 4;
    const int row_lo  = p_start / Wd;
    const int row_hi  = (p_start + F4_PER_BLOCK * 4 - 1) / Wd;

    if (threadIdx.x == 0) scount = 0;
    __syncthreads();

    // ---- derive this image's row-overlapping boxes (bit-identical f32 math)
    if (threadIdx.x < M) {
        const float4 bb = ((const float4*)bboxes)[threadIdx.x];
        if (batch_idx[threadIdx.x] == img) {
            float cx = bb.x * 640.0f, cy = bb.y * 640.0f;
            float bw = bb.z * 640.0f, bh = bb.w * 640.0f;
            float x1f = fminf(fmaxf(cx - bw * 0.5f, 0.0f), 639.0f);
            float y1f = fminf(fmaxf(cy - bh * 0.5f, 0.0f), 639.0f);
            float x2f = fminf(fmaxf(cx + bw * 0.5f, 0.0f), 639.0f);
            float y2f = fminf(fmaxf(cy + bh * 0.5f, 0.0f), 639.0f);
            int y1 = (int)y1f, y2 = (int)y2f;
            if (y1 <= row_hi && y2 >= row_lo) {
                ushort4 bx;
                bx.x = (unsigned short)(int)x1f;
                bx.y = (unsigned short)y1;
                bx.z = (unsigned short)(int)x2f;
                bx.w = (unsigned short)y2;
                int slot = atomicAdd(&scount, 1);  // LDS; order-independent union
                sbox[slot] = bx;
            }
        }
    }
    __syncthreads();
    const int  ncnt = scount;
    const bool det  = (is_seg[img] == 0);

    const float4* __restrict__ xin =
        (const float4*)(seg_preds + (size_t)img * H * Wd);

    // ---- streaming BCE partial (identical math to R1/R2: absmax was 0.0)
    float acc = 0.0f;
    #pragma unroll
    for (int k = 0; k < 4; ++k) {
        const int    f4 = chunk * F4_PER_BLOCK + k * 256 + threadIdx.x;
        const float4 v  = xin[f4];
        const int p   = f4 * 4;
        const int row = p / Wd;
        const int col = p - row * Wd;

        unsigned covm = 0u;
        if (det) {
            for (int i = 0; i < ncnt; ++i) {
                ushort4 bx = sbox[i];
                if (row >= (int)bx.y && row <= (int)bx.w) {
                    int lo = max((int)bx.x - col, 0);
                    int hi = min((int)bx.z - col, 3);
                    if (lo <= hi) covm |= ((1u << (hi - lo + 1)) - 1u) << lo;
                    if (covm == 0xFu) break;
                }
            }
        }
        const float vals[4] = {v.x, v.y, v.z, v.w};
        #pragma unroll
        for (int j = 0; j < 4; ++j) {
            float xv = vals[j];
            float a  = fabsf(xv);
            float sp = __logf(1.0f + __expf(-a));
            float term = fmaxf(xv, 0.0f) + sp;
            if (covm & (1u << j)) term -= xv;
            acc += term;
        }
    }

    // ---- block reduce (wave64 shuffle, then 4 waves)
    for (int off = 32; off > 0; off >>= 1)
        acc += __shfl_down(acc, off, 64);
    const int lane = threadIdx.x & 63;
    const int wid  = threadIdx.x >> 6;
    if (lane == 0) wsum[wid] = acc;
    __syncthreads();
    if (threadIdx.x == 0)
        partials[blockIdx.x] = wsum[0] + wsum[1] + wsum[2] + wsum[3];
}

// ---------------------------------------------------------------------------
// Kernel 2: deterministic f64 reduction of partials -> final scalar.
// ---------------------------------------------------------------------------
__global__ __launch_bounds__(256) void finalize(
    const float* __restrict__ partials,
    const unsigned char* __restrict__ is_seg,
    float* __restrict__ out)
{
    __shared__ double sd[256];
    double s = 0.0;
    // 3200 floats = 800 float4, vectorized, fixed order per thread
    const float4* p4 = (const float4*)partials;
    for (int i = threadIdx.x; i < NBLK / 4; i += 256) {
        float4 v = p4[i];
        s += (double)v.x + (double)v.y + (double)v.z + (double)v.w;
    }
    sd[threadIdx.x] = s;
    __syncthreads();
    for (int off = 128; off > 0; off >>= 1) {
        if (threadIdx.x < off) sd[threadIdx.x] += sd[threadIdx.x + off];
        __syncthreads();
    }
    if (threadIdx.x == 0) {
        int nd = 0;
        for (int b = 0; b < B; ++b) nd += (is_seg[b] == 0) ? 1 : 0;
        double hd   = (nd > 0) ? 1.0 : 0.0;
        double mean = sd[0] / (double)((size_t)B * H * Wd);
        out[0] = (float)(0.1 * mean * hd);
    }
}

extern "C" void kernel_launch(void* const* d_in, const int* in_sizes, int n_in,
                              void* d_out, int out_size, void* d_ws, size_t ws_size,
                              hipStream_t stream)
{
    const float*         seg_preds = (const float*)d_in[0];
    const float*         bboxes    = (const float*)d_in[1];
    const int*           batch_idx = (const int*)d_in[2];
    const unsigned char* is_seg    = (const unsigned char*)d_in[3];

    float* partials = (float*)((char*)d_ws + WS_PARTIALS_OFF);
    float* out      = (float*)d_out;

    bce_partial<<<NBLK, 256, 0, stream>>>(seg_preds, bboxes, batch_idx, is_seg,
                                          partials);
    finalize<<<1, 256, 0, stream>>>(partials, is_seg, out);
}